// Round 1
// baseline (175.938 us; speedup 1.0000x reference)
//
#include <hip/hip_runtime.h>
#include <math.h>

// my_ceil(y) = sum_{k=1..150} sigmoid(100(y-k)) + sigmoid(100(y+k)) - 150
// Closed form: with R=100 every sigmoid saturates to 0/1 (fp32-exact) outside
// |arg|<0.35, and at most ONE integer offset lies in that window around y.
//   r = rint(y), d = y - r, s = sigmoid(100 d)
//   r >=  1 : (r-1) + s
//   r <= -1 : r + s
//   r ==  0 : 0            (offset 0 excluded from the sum)
//   clamp to [-150, 150]   (transition integer outside the 1..150 offset set)
__device__ __forceinline__ float my_ceil1(float y) {
    float r = rintf(y);
    float d = y - r;
    float z = 100.0f * d;
    float s = 1.0f / (1.0f + __expf(-z));   // sigmoid(100 d); no overflow: |z| <= 50
    float f = (r >= 1.0f) ? (r - 1.0f + s)
            : (r <= -1.0f) ? (r + s)
            : 0.0f;
    return fminf(fmaxf(f, -150.0f), 150.0f);
}

__global__ __launch_bounds__(256) void quan_ceil_kernel(
        const float* __restrict__ x,
        const float* __restrict__ kern,   // 12 floats (C=12), broadcast over NHW
        float* __restrict__ out,
        int n4) {                          // number of float4 elements
    // 12 channels = 3 aligned float4 groups; a float4 at index j covers
    // channels [4*(j%3) .. 4*(j%3)+3].
    const float4* k4 = reinterpret_cast<const float4*>(kern);
    const float4 kk0 = k4[0];
    const float4 kk1 = k4[1];
    const float4 kk2 = k4[2];

    const float4* __restrict__ x4 = reinterpret_cast<const float4*>(x);
    float4* __restrict__ o4 = reinterpret_cast<float4*>(out);

    int stride = gridDim.x * blockDim.x;
    for (int j = blockIdx.x * blockDim.x + threadIdx.x; j < n4; j += stride) {
        float4 v = x4[j];
        int g = j % 3;
        // ternary select, NOT a runtime-indexed array (avoids scratch spill)
        float4 kc = (g == 0) ? kk0 : (g == 1) ? kk1 : kk2;
        float4 o;
        o.x = my_ceil1(v.x * kc.x);
        o.y = my_ceil1(v.y * kc.y);
        o.z = my_ceil1(v.z * kc.z);
        o.w = my_ceil1(v.w * kc.w);
        o4[j] = o;
    }
}

extern "C" void kernel_launch(void* const* d_in, const int* in_sizes, int n_in,
                              void* d_out, int out_size, void* d_ws, size_t ws_size,
                              hipStream_t stream) {
    const float* x = (const float*)d_in[0];
    const float* kern = (const float*)d_in[1];
    float* out = (float*)d_out;

    int n = in_sizes[0];          // 128*128*128*12 = 25,165,824 (divisible by 12 and 4)
    int n4 = n / 4;               // 6,291,456 float4s

    const int block = 256;
    // memory-bound: ~2048 blocks (8 per CU) + grid-stride (Guideline 11)
    int grid = (n4 + block - 1) / block;
    if (grid > 2048) grid = 2048;

    quan_ceil_kernel<<<grid, block, 0, stream>>>(x, kern, out, n4);
}

// Round 3
// 172.750 us; speedup vs baseline: 1.0185x; 1.0185x over previous
//
#include <hip/hip_runtime.h>
#include <math.h>

// my_ceil(y) = sum_{k=1..150} sigmoid(100(y-k)) + sigmoid(100(y+k)) - 150
// Closed form (verified passing in round 1): with R=100 every sigmoid
// saturates to fp32-exact 0/1 outside |arg|<~35, and at most ONE integer
// offset lies in the transition window around y.
//   r = rint(y), d = y - r, s = sigmoid(100 d)
//   r >=  1 : (r-1) + s
//   r <= -1 : r + s
//   r ==  0 : 0            (offset 0 excluded from the sum)
//   clamp to [-150, 150]   (transition integer outside the 1..150 offset set)
__device__ __forceinline__ float my_ceil1(float y) {
    float r = rintf(y);
    float d = y - r;
    float e = __expf(-100.0f * d);                 // v_mul + v_exp_f32
    float s = __builtin_amdgcn_rcpf(1.0f + e);     // 1-instr reciprocal (~1 ulp)
    float f = (r >= 1.0f) ? (r - 1.0f + s)
            : (r <= -1.0f) ? (r + s)
            : 0.0f;
    return fminf(fmaxf(f, -150.0f), 150.0f);
}

// One thread = 2 independent float4s (j and j+half) -> 2 loads in flight per
// lane (ILP), full grid (no grid-stride loop) -> max TLP. half % 3 == 0, so
// both float4s fall in the same channel-group (one %3 per thread).
__global__ __launch_bounds__(256) void quan_ceil_kernel(
        const float4* __restrict__ x4,
        const float* __restrict__ kern,   // 12 floats (C=12), broadcast
        float4* __restrict__ o4,
        int half) {                        // n4/2, divisible by 3
    int j = blockIdx.x * blockDim.x + threadIdx.x;
    if (j >= half) return;

    const float4* k4 = reinterpret_cast<const float4*>(kern);
    int g = j % 3;
    // ternary select, NOT a runtime-indexed array (avoids scratch, rule #20)
    float4 kc = (g == 0) ? k4[0] : (g == 1) ? k4[1] : k4[2];

    float4 a = x4[j];          // both loads independent -> issued back-to-back
    float4 b = x4[j + half];

    float4 oa, ob;
    oa.x = my_ceil1(a.x * kc.x);
    oa.y = my_ceil1(a.y * kc.y);
    oa.z = my_ceil1(a.z * kc.z);
    oa.w = my_ceil1(a.w * kc.w);
    ob.x = my_ceil1(b.x * kc.x);
    ob.y = my_ceil1(b.y * kc.y);
    ob.z = my_ceil1(b.z * kc.z);
    ob.w = my_ceil1(b.w * kc.w);

    o4[j] = oa;
    o4[j + half] = ob;
}

extern "C" void kernel_launch(void* const* d_in, const int* in_sizes, int n_in,
                              void* d_out, int out_size, void* d_ws, size_t ws_size,
                              hipStream_t stream) {
    const float* x = (const float*)d_in[0];
    const float* kern = (const float*)d_in[1];
    float* out = (float*)d_out;

    int n = in_sizes[0];   // 128*128*128*12 = 25,165,824
    int n4 = n / 4;        // 6,291,456 float4s
    int half = n4 / 2;     // 3,145,728  (divisible by 3: j and j+half share %3)

    const int block = 256;
    int grid = (half + block - 1) / block;   // 12288 blocks — full coverage

    quan_ceil_kernel<<<grid, block, 0, stream>>>(
        reinterpret_cast<const float4*>(x), kern,
        reinterpret_cast<float4*>(out), half);
}